// Round 1
// baseline (210.708 us; speedup 1.0000x reference)
//
#include <hip/hip_runtime.h>
#include <hip/hip_bf16.h>
#include <stdint.h>

// Problem constants (B=4, T=2048, C=512, H=8, D=64)
constexpr int Bn = 4;
constexpr int Tn = 2048;
constexpr int Cn = 512;
constexpr int Hn = 8;
constexpr int Dn = 64;
constexpr int BT = Bn * Tn;          // 8192
constexpr int NQKV = 3 * Cn;         // 1536

typedef __attribute__((ext_vector_type(4))) float  f32x4;
typedef __attribute__((ext_vector_type(8))) short  s16x8;
typedef __attribute__((ext_vector_type(4))) short  s16x4;

__device__ __forceinline__ short f2bs(float f) {
    __hip_bfloat16 h = __float2bfloat16(f);
    return *reinterpret_cast<short*>(&h);
}

// ---------------- conversion / setup kernels ----------------

__global__ __launch_bounds__(256) void k_conv_x(const float* __restrict__ x,
                                                short* __restrict__ xb) {
    int i = blockIdx.x * 256 + threadIdx.x;          // one float4 per thread
    f32x4 v = reinterpret_cast<const f32x4*>(x)[i];
    s16x4 o;
    o[0] = f2bs(v[0]); o[1] = f2bs(v[1]); o[2] = f2bs(v[2]); o[3] = f2bs(v[3]);
    reinterpret_cast<s16x4*>(xb)[i] = o;
}

// w [512][N] fp32 -> wt [N][512] bf16
__global__ __launch_bounds__(256) void k_wT(const float* __restrict__ w,
                                            short* __restrict__ wt, int N) {
    int i = blockIdx.x * 256 + threadIdx.x;
    int k = i / N, n = i - k * N;
    wt[n * 512 + k] = f2bs(w[i]);
}

__global__ __launch_bounds__(256) void k_rope(float* __restrict__ cosT,
                                              float* __restrict__ sinT) {
    int i = blockIdx.x * 256 + threadIdx.x;          // < T*D
    int t = i >> 6, d = i & 63;
    // inv_freq = 10000^(-(d&31)/32) = exp2(-(d&31)*log2(10000)/32)
    float inv = exp2f(-(float)(d & 31) * 0.41524101186f);
    float fr = (float)t * inv;
    cosT[i] = cosf(fr);
    sinT[i] = sinf(fr);
}

// ---------------- GEMM (64x64 tile, 4 waves, 16x16x32 bf16 MFMA) ----------------
// A: [M][512] bf16 row-major.  Bt: [N][512] bf16 (pre-transposed weights).
// MODE 0: epilogue = RoPE + scatter to Q/K/V [B*H][T][D] bf16.
// MODE 1: epilogue = plain fp32 store to out [M][512].

template <int MODE>
__global__ __launch_bounds__(256) void gemm_kernel(
    const short* __restrict__ A, const short* __restrict__ Bt,
    const float* __restrict__ cosT, const float* __restrict__ sinT,
    short* __restrict__ Qb, short* __restrict__ Kb, short* __restrict__ Vb,
    float* __restrict__ outF) {
    const int m0 = blockIdx.y * 64;
    const int n0 = blockIdx.x * 64;
    const int tid = threadIdx.x;
    const int w = tid >> 6, lane = tid & 63;
    const int qi = lane & 15, g = lane >> 4;

    // LDS layout: [colblk(4)][row(64)][8] — 16B per (colblk,row) chunk
    __shared__ short As[4 * 64 * 8];
    __shared__ short Bs[4 * 64 * 8];

    f32x4 acc[4];
#pragma unroll
    for (int nt = 0; nt < 4; ++nt) acc[nt] = (f32x4){0.f, 0.f, 0.f, 0.f};

    const int srow = tid >> 2, scb = tid & 3;

    for (int k0 = 0; k0 < 512; k0 += 32) {
        *(s16x8*)&As[(scb * 64 + srow) * 8] =
            *(const s16x8*)&A[(size_t)(m0 + srow) * 512 + k0 + scb * 8];
        *(s16x8*)&Bs[(scb * 64 + srow) * 8] =
            *(const s16x8*)&Bt[(size_t)(n0 + srow) * 512 + k0 + scb * 8];
        __syncthreads();
        s16x8 af = *(const s16x8*)&As[(g * 64 + 16 * w + qi) * 8];
#pragma unroll
        for (int nt = 0; nt < 4; ++nt) {
            s16x8 bf = *(const s16x8*)&Bs[(g * 64 + nt * 16 + qi) * 8];
            acc[nt] = __builtin_amdgcn_mfma_f32_16x16x32_bf16(af, bf, acc[nt], 0, 0, 0);
        }
        __syncthreads();
    }

    if (MODE == 1) {
#pragma unroll
        for (int nt = 0; nt < 4; ++nt)
#pragma unroll
            for (int r = 0; r < 4; ++r)
                outF[(size_t)(m0 + 16 * w + 4 * g + r) * 512 + n0 + nt * 16 + qi] =
                    acc[nt][r];
    } else {
        // n-tile (64 wide) lies entirely inside one {q,k,v} segment of one head
        const int h = n0 / 192;
        const int seg = (n0 >> 6) % 3;               // 0=q 1=k 2=v
        const int b = m0 >> 11;                      // m0 / 2048
        const int tb = (m0 & 2047) + 16 * w;
        const size_t headbase = (size_t)(b * Hn + h) * Tn;
        if (seg == 2) {
#pragma unroll
            for (int nt = 0; nt < 4; ++nt)
#pragma unroll
                for (int r = 0; r < 4; ++r) {
                    int t = tb + 4 * g + r;
                    Vb[(headbase + t) * Dn + nt * 16 + qi] = f2bs(acc[nt][r]);
                }
        } else {
            short* dst = (seg == 0) ? Qb : Kb;
#pragma unroll
            for (int nt = 0; nt < 4; ++nt)
#pragma unroll
                for (int r = 0; r < 4; ++r) {
                    int t = tb + 4 * g + r;
                    int d = nt * 16 + qi;
                    float val = acc[nt][r];
                    float pv = (nt < 2) ? -acc[nt + 2][r] : acc[nt - 2][r];
                    float cc = cosT[t * 64 + d], ss = sinT[t * 64 + d];
                    dst[(headbase + t) * Dn + d] = f2bs(val * cc + pv * ss);
                }
        }
    }
}

// ---------------- causal flash attention ----------------
// Grid: (T/64 q-tiles, B*H). Block: 4 waves; wave w owns 16 queries.
// Swapped QK^T: S^T = K·Q so softmax row = per-lane column qi; P stays lane-local
// for the PV MFMA A-operand. V^T in LDS for the PV B-operand.

__global__ __launch_bounds__(256) void attn_kernel(const short* __restrict__ Qb,
                                                   const short* __restrict__ Kb,
                                                   const short* __restrict__ Vb,
                                                   short* __restrict__ AO) {
    const int bh = blockIdx.y;
    const int q0 = blockIdx.x * 64;
    const int tid = threadIdx.x;
    const int w = tid >> 6, lane = tid & 63;
    const int qi = lane & 15, g = lane >> 4;
    const int b = bh >> 3, h = bh & 7;

    __shared__ short Ks[8 * 32 * 8];    // [dblk(8)][key(32)][8]
    __shared__ short VTs[64 * 36];      // [d(64)][kv(32) pad 36]

    const int qrow = q0 + 16 * w + qi;
    const size_t qbase = ((size_t)bh * Tn + qrow) * Dn;
    const s16x8 qf0 = *(const s16x8*)&Qb[qbase + 8 * g];
    const s16x8 qf1 = *(const s16x8*)&Qb[qbase + 32 + 8 * g];

    f32x4 O[4];
#pragma unroll
    for (int dt = 0; dt < 4; ++dt) O[dt] = (f32x4){0.f, 0.f, 0.f, 0.f};
    float mrow = -1e30f, lrow = 0.f;

    const float sc = 0.125f * 1.44269504f;   // scale * log2(e)
    const int nkv = (q0 >> 5) + 2;           // 32-key tiles covering keys <= q0+63
    const f32x4 zero4 = {0.f, 0.f, 0.f, 0.f};

    const int skey = tid >> 3, sdb = tid & 7;   // staging decomposition

    for (int it = 0; it < nkv; ++it) {
        const int kv0 = it * 32;
        // ---- stage K tile and V^T tile ----
        {
            const size_t grow = ((size_t)bh * Tn + kv0 + skey) * Dn + sdb * 8;
            *(s16x8*)&Ks[(sdb * 32 + skey) * 8] = *(const s16x8*)&Kb[grow];
            s16x8 vv = *(const s16x8*)&Vb[grow];
#pragma unroll
            for (int j = 0; j < 8; ++j) VTs[(sdb * 8 + j) * 36 + skey] = vv[j];
        }
        __syncthreads();

        // ---- S^T = K·Q (2 key-subtiles × 2 d-halves) ----
        s16x8 k00 = *(const s16x8*)&Ks[((0 + g) * 32 + qi) * 8];
        s16x8 k10 = *(const s16x8*)&Ks[((4 + g) * 32 + qi) * 8];
        f32x4 s0 = __builtin_amdgcn_mfma_f32_16x16x32_bf16(k00, qf0, zero4, 0, 0, 0);
        s0 = __builtin_amdgcn_mfma_f32_16x16x32_bf16(k10, qf1, s0, 0, 0, 0);
        s16x8 k01 = *(const s16x8*)&Ks[((0 + g) * 32 + 16 + qi) * 8];
        s16x8 k11 = *(const s16x8*)&Ks[((4 + g) * 32 + 16 + qi) * 8];
        f32x4 s1 = __builtin_amdgcn_mfma_f32_16x16x32_bf16(k01, qf0, zero4, 0, 0, 0);
        s1 = __builtin_amdgcn_mfma_f32_16x16x32_bf16(k11, qf1, s1, 0, 0, 0);

        // ---- causal mask + scale (log2 domain) ----
        float sv[8];
#pragma unroll
        for (int r = 0; r < 4; ++r) {
            int key0 = kv0 + 4 * g + r;
            int key1 = kv0 + 16 + 4 * g + r;
            sv[r]     = (key0 <= qrow) ? s0[r] * sc : -1e30f;
            sv[4 + r] = (key1 <= qrow) ? s1[r] * sc : -1e30f;
        }
        // ---- online softmax (row = fixed qi, reduce over 4 lane-groups) ----
        float pm = sv[0];
#pragma unroll
        for (int e = 1; e < 8; ++e) pm = fmaxf(pm, sv[e]);
        pm = fmaxf(pm, __shfl_xor(pm, 16));
        pm = fmaxf(pm, __shfl_xor(pm, 32));
        float mnew = fmaxf(mrow, pm);
        float f = exp2f(mrow - mnew);
        mrow = mnew;
        float ps = 0.f;
#pragma unroll
        for (int e = 0; e < 8; ++e) { sv[e] = exp2f(sv[e] - mnew); ps += sv[e]; }
        ps += __shfl_xor(ps, 16);
        ps += __shfl_xor(ps, 32);
        lrow = lrow * f + ps;
        // ---- rescale O (factors are per output-row q=4g+r) ----
#pragma unroll
        for (int r = 0; r < 4; ++r) {
            float fr = __shfl(f, 4 * g + r);
            O[0][r] *= fr; O[1][r] *= fr; O[2][r] *= fr; O[3][r] *= fr;
        }
        // ---- P -> bf16 A-fragment (lane-local by construction) ----
        s16x8 pf;
#pragma unroll
        for (int e = 0; e < 8; ++e) pf[e] = f2bs(sv[e]);
        // ---- O += P·V ----
#pragma unroll
        for (int dt = 0; dt < 4; ++dt) {
            int d = dt * 16 + qi;
            s16x4 v0 = *(const s16x4*)&VTs[d * 36 + 4 * g];
            s16x4 v1 = *(const s16x4*)&VTs[d * 36 + 16 + 4 * g];
            s16x8 vf = __builtin_shufflevector(v0, v1, 0, 1, 2, 3, 4, 5, 6, 7);
            O[dt] = __builtin_amdgcn_mfma_f32_16x16x32_bf16(pf, vf, O[dt], 0, 0, 0);
        }
        __syncthreads();
    }

    // ---- normalize + store (AO is [B*T][C] bf16, head-concatenated) ----
#pragma unroll
    for (int r = 0; r < 4; ++r) {
        float li = __shfl(lrow, 4 * g + r);
        float inv = 1.f / li;
        int t = q0 + 16 * w + 4 * g + r;
#pragma unroll
        for (int dt = 0; dt < 4; ++dt)
            AO[((size_t)(b * Tn + t)) * Cn + h * 64 + dt * 16 + qi] =
                f2bs(O[dt][r] * inv);
    }
}

// ---------------- launcher ----------------

extern "C" void kernel_launch(void* const* d_in, const int* in_sizes, int n_in,
                              void* d_out, int out_size, void* d_ws, size_t ws_size,
                              hipStream_t stream) {
    const float* x = (const float*)d_in[0];
    const float* Wqkv = (const float*)d_in[1];
    const float* Wproj = (const float*)d_in[2];
    float* out = (float*)d_out;

    char* ws = (char*)d_ws;
    size_t o = 0;
    short* xb = (short*)(ws + o);      o += (size_t)BT * Cn * 2;      // 8MB (aliased as AO later)
    short* wqkvT = (short*)(ws + o);   o += (size_t)NQKV * Cn * 2;    // 1.5MB
    short* wprojT = (short*)(ws + o);  o += (size_t)Cn * Cn * 2;      // 0.5MB
    short* Qb = (short*)(ws + o);      o += (size_t)Bn * Hn * Tn * Dn * 2;  // 8MB
    short* Kb = (short*)(ws + o);      o += (size_t)Bn * Hn * Tn * Dn * 2;  // 8MB
    short* Vb = (short*)(ws + o);      o += (size_t)Bn * Hn * Tn * Dn * 2;  // 8MB
    float* cosT = (float*)(ws + o);    o += (size_t)Tn * Dn * 4;      // 0.5MB
    float* sinT = (float*)(ws + o);    o += (size_t)Tn * Dn * 4;      // 0.5MB

    k_conv_x<<<BT * Cn / 4 / 256, 256, 0, stream>>>(x, xb);
    k_wT<<<512 * NQKV / 256, 256, 0, stream>>>(Wqkv, wqkvT, NQKV);
    k_wT<<<512 * Cn / 256, 256, 0, stream>>>(Wproj, wprojT, Cn);
    k_rope<<<Tn * Dn / 256, 256, 0, stream>>>(cosT, sinT);

    gemm_kernel<0><<<dim3(NQKV / 64, BT / 64), 256, 0, stream>>>(
        xb, wqkvT, cosT, sinT, Qb, Kb, Vb, nullptr);

    attn_kernel<<<dim3(Tn / 64, Bn * Hn), 256, 0, stream>>>(Qb, Kb, Vb, xb /*AO alias*/);

    gemm_kernel<1><<<dim3(Cn / 64, BT / 64), 256, 0, stream>>>(
        xb /*AO*/, wprojT, nullptr, nullptr, nullptr, nullptr, nullptr, out);
}

// Round 2
// 164.568 us; speedup vs baseline: 1.2804x; 1.2804x over previous
//
#include <hip/hip_runtime.h>
#include <hip/hip_bf16.h>
#include <stdint.h>

// Problem constants (B=4, T=2048, C=512, H=8, D=64)
constexpr int Bn = 4;
constexpr int Tn = 2048;
constexpr int Cn = 512;
constexpr int Hn = 8;
constexpr int Dn = 64;
constexpr int BT = Bn * Tn;          // 8192
constexpr int NQKV = 3 * Cn;         // 1536

typedef __attribute__((ext_vector_type(4))) float  f32x4;
typedef __attribute__((ext_vector_type(8))) short  s16x8;
typedef __attribute__((ext_vector_type(4))) short  s16x4;

__device__ __forceinline__ short f2bs(float f) {
    __hip_bfloat16 h = __float2bfloat16(f);
    return *reinterpret_cast<short*>(&h);
}

// ---------------- conversion / setup kernels ----------------

__global__ __launch_bounds__(256) void k_conv_x(const float* __restrict__ x,
                                                short* __restrict__ xb) {
    int i = blockIdx.x * 256 + threadIdx.x;          // one float4 per thread
    f32x4 v = reinterpret_cast<const f32x4*>(x)[i];
    s16x4 o;
    o[0] = f2bs(v[0]); o[1] = f2bs(v[1]); o[2] = f2bs(v[2]); o[3] = f2bs(v[3]);
    reinterpret_cast<s16x4*>(xb)[i] = o;
}

// w [512][N] fp32 -> wt [N][512] bf16
__global__ __launch_bounds__(256) void k_wT(const float* __restrict__ w,
                                            short* __restrict__ wt, int N) {
    int i = blockIdx.x * 256 + threadIdx.x;
    int k = i / N, n = i - k * N;
    wt[n * 512 + k] = f2bs(w[i]);
}

__global__ __launch_bounds__(256) void k_rope(float* __restrict__ cosT,
                                              float* __restrict__ sinT) {
    int i = blockIdx.x * 256 + threadIdx.x;          // < T*D
    int t = i >> 6, d = i & 63;
    // inv_freq = 10000^(-(d&31)/32) = exp2(-(d&31)*log2(10000)/32)
    float inv = exp2f(-(float)(d & 31) * 0.41524101186f);
    float fr = (float)t * inv;
    cosT[i] = cosf(fr);
    sinT[i] = sinf(fr);
}

// ---------------- GEMM (64x64 tile, 4 waves, 16x16x32 bf16 MFMA) ----------------
// A: [M][512] bf16 row-major.  Bt: [N][512] bf16 (pre-transposed weights).
// MODE 0: epilogue = RoPE + scatter Q/K to [B*H][T][D], V to transposed+permuted
//         Vt [B*H][D][Tperm] (fragment order for attn's PV B-operand).
// MODE 1: epilogue = plain fp32 store to out [M][512].

template <int MODE>
__global__ __launch_bounds__(256) void gemm_kernel(
    const short* __restrict__ A, const short* __restrict__ Bt,
    const float* __restrict__ cosT, const float* __restrict__ sinT,
    short* __restrict__ Qb, short* __restrict__ Kb, short* __restrict__ Vt,
    float* __restrict__ outF) {
    const int m0 = blockIdx.y * 64;
    const int n0 = blockIdx.x * 64;
    const int tid = threadIdx.x;
    const int w = tid >> 6, lane = tid & 63;
    const int qi = lane & 15, g = lane >> 4;

    // LDS layout: [colblk(4)][row(64)][8] — 16B per (colblk,row) chunk
    __shared__ short As[4 * 64 * 8];
    __shared__ short Bs[4 * 64 * 8];

    f32x4 acc[4];
#pragma unroll
    for (int nt = 0; nt < 4; ++nt) acc[nt] = (f32x4){0.f, 0.f, 0.f, 0.f};

    const int srow = tid >> 2, scb = tid & 3;

    for (int k0 = 0; k0 < 512; k0 += 32) {
        *(s16x8*)&As[(scb * 64 + srow) * 8] =
            *(const s16x8*)&A[(size_t)(m0 + srow) * 512 + k0 + scb * 8];
        *(s16x8*)&Bs[(scb * 64 + srow) * 8] =
            *(const s16x8*)&Bt[(size_t)(n0 + srow) * 512 + k0 + scb * 8];
        __syncthreads();
        s16x8 af = *(const s16x8*)&As[(g * 64 + 16 * w + qi) * 8];
#pragma unroll
        for (int nt = 0; nt < 4; ++nt) {
            s16x8 bf = *(const s16x8*)&Bs[(g * 64 + nt * 16 + qi) * 8];
            acc[nt] = __builtin_amdgcn_mfma_f32_16x16x32_bf16(af, bf, acc[nt], 0, 0, 0);
        }
        __syncthreads();
    }

    if (MODE == 1) {
#pragma unroll
        for (int nt = 0; nt < 4; ++nt)
#pragma unroll
            for (int r = 0; r < 4; ++r)
                outF[(size_t)(m0 + 16 * w + 4 * g + r) * 512 + n0 + nt * 16 + qi] =
                    acc[nt][r];
    } else {
        // n-tile (64 wide) lies entirely inside one {q,k,v} segment of one head
        const int h = n0 / 192;
        const int seg = (n0 >> 6) % 3;               // 0=q 1=k 2=v
        const int b = m0 >> 11;                      // m0 / 2048
        const int tb = (m0 & 2047) + 16 * w;
        if (seg == 2) {
            // V transposed + fragment-permuted: Vt[bh][d][ (t&~31) + g2*8 + sub2*4 + r2 ]
            const size_t vbase = (size_t)(b * Hn + h) * Dn;
#pragma unroll
            for (int nt = 0; nt < 4; ++nt)
#pragma unroll
                for (int r = 0; r < 4; ++r) {
                    int t = tb + 4 * g + r;
                    int d = nt * 16 + qi;
                    int o = t & 31;
                    int j = (t & ~31) + ((o >> 2) & 3) * 8 + (o >> 4) * 4 + (o & 3);
                    Vt[(vbase + d) * Tn + j] = f2bs(acc[nt][r]);
                }
        } else {
            short* dst = (seg == 0) ? Qb : Kb;
            const size_t headbase = (size_t)(b * Hn + h) * Tn;
#pragma unroll
            for (int nt = 0; nt < 4; ++nt)
#pragma unroll
                for (int r = 0; r < 4; ++r) {
                    int t = tb + 4 * g + r;
                    int d = nt * 16 + qi;
                    float val = acc[nt][r];
                    float pv = (nt < 2) ? -acc[nt + 2][r] : acc[nt - 2][r];
                    float cc = cosT[t * 64 + d], ss = sinT[t * 64 + d];
                    dst[(headbase + t) * Dn + d] = f2bs(val * cc + pv * ss);
                }
        }
    }
}

// ---------------- causal flash attention (LDS-free, 1 wave / 32 queries) ----------
// Grid: 1D, 2048 single-wave blocks. gid -> bh = gid&31, qt = 63 - (gid>>5)
// (heaviest causal tiles dispatch first, all bh interleaved for balance).
// Swapped QK^T: S^T = K·Q per 16-query subtile; softmax row = lane column qi,
// reduced across the 4 lane-groups with shfl_xor. P stays lane-local for PV's
// A-operand; V is pre-transposed+permuted so PV's B-fragment is one 16B load.

__global__ __launch_bounds__(64) void attn_kernel(const short* __restrict__ Qb,
                                                  const short* __restrict__ Kb,
                                                  const short* __restrict__ Vt,
                                                  short* __restrict__ AO) {
    const int gid = blockIdx.x;
    const int bh = gid & 31;
    const int qt = (Tn / 32 - 1) - (gid >> 5);
    const int lane = threadIdx.x;
    const int qi = lane & 15, g = lane >> 4;
    const int b = bh >> 3, h = bh & 7;

    const short* Qh = Qb + (size_t)bh * Tn * Dn;
    const short* Kh = Kb + (size_t)bh * Tn * Dn;
    const short* Vh = Vt + (size_t)bh * Dn * Tn;

    s16x8 qf[2][2];
#pragma unroll
    for (int qs = 0; qs < 2; ++qs)
#pragma unroll
        for (int dh = 0; dh < 2; ++dh)
            qf[qs][dh] = *(const s16x8*)&Qh[(size_t)(qt * 32 + qs * 16 + qi) * Dn +
                                            dh * 32 + g * 8];

    f32x4 O[2][4];
#pragma unroll
    for (int qs = 0; qs < 2; ++qs)
#pragma unroll
        for (int dt = 0; dt < 4; ++dt) O[qs][dt] = (f32x4){0.f, 0.f, 0.f, 0.f};
    float m[2] = {-1e30f, -1e30f};
    float l[2] = {0.f, 0.f};

    const float sc = 0.125f * 1.44269504f;   // 1/sqrt(D) * log2(e)
    const int nch = ((qt * 32 + 31) >> 6) + 1;
    const f32x4 z4 = {0.f, 0.f, 0.f, 0.f};

    for (int ch = 0; ch < nch; ++ch) {
        const int kv0 = ch * 64;
        // ---- S^T = K·Q : 4 key-subtiles x 2 query-subtiles ----
        f32x4 s[2][4];
#pragma unroll
        for (int sub = 0; sub < 4; ++sub) {
            const size_t krow = (size_t)(kv0 + sub * 16 + qi) * Dn;
            s16x8 ka = *(const s16x8*)&Kh[krow + g * 8];
            s16x8 kc = *(const s16x8*)&Kh[krow + 32 + g * 8];
#pragma unroll
            for (int qs = 0; qs < 2; ++qs) {
                f32x4 t0 = __builtin_amdgcn_mfma_f32_16x16x32_bf16(ka, qf[qs][0], z4, 0, 0, 0);
                s[qs][sub] = __builtin_amdgcn_mfma_f32_16x16x32_bf16(kc, qf[qs][1], t0, 0, 0, 0);
            }
        }

        s16x8 pf[2][2];
#pragma unroll
        for (int qs = 0; qs < 2; ++qs) {
            const int qsbase = qt * 32 + qs * 16;
            const int qrow = qsbase + qi;
            float sv[16];
            if (kv0 + 63 <= qsbase) {           // interior chunk: no masking needed
#pragma unroll
                for (int e = 0; e < 16; ++e) sv[e] = s[qs][e >> 2][e & 3] * sc;
            } else {
#pragma unroll
                for (int sub = 0; sub < 4; ++sub)
#pragma unroll
                    for (int r = 0; r < 4; ++r) {
                        int key = kv0 + sub * 16 + 4 * g + r;
                        sv[sub * 4 + r] = (key <= qrow) ? s[qs][sub][r] * sc : -1e30f;
                    }
            }
            // row max (row = query qi; reduce in-lane then across 4 g-groups)
            float pm = sv[0];
#pragma unroll
            for (int e = 1; e < 16; ++e) pm = fmaxf(pm, sv[e]);
            pm = fmaxf(pm, __shfl_xor(pm, 16));
            pm = fmaxf(pm, __shfl_xor(pm, 32));
            float mn = m[qs];
            if (!__all(pm <= mn + 8.0f)) {      // defer-max (log2 domain, THR=8)
                mn = fmaxf(mn, pm);
                float f = exp2f(m[qs] - mn);
                m[qs] = mn;
                l[qs] *= f;
#pragma unroll
                for (int r = 0; r < 4; ++r) {
                    float fr = __shfl(f, 4 * g + r);
#pragma unroll
                    for (int dt = 0; dt < 4; ++dt) O[qs][dt][r] *= fr;
                }
            }
            float ps = 0.f;
#pragma unroll
            for (int e = 0; e < 16; ++e) { sv[e] = exp2f(sv[e] - mn); ps += sv[e]; }
            ps += __shfl_xor(ps, 16);
            ps += __shfl_xor(ps, 32);
            l[qs] += ps;
#pragma unroll
            for (int c = 0; c < 2; ++c)
#pragma unroll
                for (int e = 0; e < 8; ++e) pf[qs][c][e] = f2bs(sv[c * 8 + e]);
        }

        // ---- O += P·V (V fragment = one 16B load from permuted Vt) ----
#pragma unroll
        for (int c = 0; c < 2; ++c)
#pragma unroll
            for (int dt = 0; dt < 4; ++dt) {
                s16x8 vf = *(const s16x8*)&Vh[(size_t)(dt * 16 + qi) * Tn +
                                              kv0 + c * 32 + g * 8];
#pragma unroll
                for (int qs = 0; qs < 2; ++qs)
                    O[qs][dt] = __builtin_amdgcn_mfma_f32_16x16x32_bf16(
                        pf[qs][c], vf, O[qs][dt], 0, 0, 0);
            }
    }

    // ---- normalize + store (AO is [B*T][C] bf16, head-concatenated) ----
#pragma unroll
    for (int qs = 0; qs < 2; ++qs)
#pragma unroll
        for (int r = 0; r < 4; ++r) {
            float li = __shfl(l[qs], 4 * g + r);
            float inv = 1.f / li;
            int t = qt * 32 + qs * 16 + 4 * g + r;
#pragma unroll
            for (int dt = 0; dt < 4; ++dt)
                AO[((size_t)(b * Tn + t)) * Cn + h * 64 + dt * 16 + qi] =
                    f2bs(O[qs][dt][r] * inv);
        }
}

// ---------------- launcher ----------------

extern "C" void kernel_launch(void* const* d_in, const int* in_sizes, int n_in,
                              void* d_out, int out_size, void* d_ws, size_t ws_size,
                              hipStream_t stream) {
    const float* x = (const float*)d_in[0];
    const float* Wqkv = (const float*)d_in[1];
    const float* Wproj = (const float*)d_in[2];
    float* out = (float*)d_out;

    char* ws = (char*)d_ws;
    size_t o = 0;
    short* xb = (short*)(ws + o);      o += (size_t)BT * Cn * 2;      // 8MB (aliased as AO later)
    short* wqkvT = (short*)(ws + o);   o += (size_t)NQKV * Cn * 2;    // 1.5MB
    short* wprojT = (short*)(ws + o);  o += (size_t)Cn * Cn * 2;      // 0.5MB
    short* Qb = (short*)(ws + o);      o += (size_t)Bn * Hn * Tn * Dn * 2;  // 8MB
    short* Kb = (short*)(ws + o);      o += (size_t)Bn * Hn * Tn * Dn * 2;  // 8MB
    short* Vt = (short*)(ws + o);      o += (size_t)Bn * Hn * Tn * Dn * 2;  // 8MB
    float* cosT = (float*)(ws + o);    o += (size_t)Tn * Dn * 4;      // 0.5MB
    float* sinT = (float*)(ws + o);    o += (size_t)Tn * Dn * 4;      // 0.5MB

    k_conv_x<<<BT * Cn / 4 / 256, 256, 0, stream>>>(x, xb);
    k_wT<<<512 * NQKV / 256, 256, 0, stream>>>(Wqkv, wqkvT, NQKV);
    k_wT<<<512 * Cn / 256, 256, 0, stream>>>(Wproj, wprojT, Cn);
    k_rope<<<Tn * Dn / 256, 256, 0, stream>>>(cosT, sinT);

    gemm_kernel<0><<<dim3(NQKV / 64, BT / 64), 256, 0, stream>>>(
        xb, wqkvT, cosT, sinT, Qb, Kb, Vt, nullptr);

    attn_kernel<<<dim3(Tn / 32 * 32), 64, 0, stream>>>(Qb, Kb, Vt, xb /*AO alias*/);

    gemm_kernel<1><<<dim3(Cn / 64, BT / 64), 256, 0, stream>>>(
        xb /*AO*/, wprojT, nullptr, nullptr, nullptr, nullptr, nullptr, out);
}

// Round 3
// 159.866 us; speedup vs baseline: 1.3180x; 1.0294x over previous
//
#include <hip/hip_runtime.h>
#include <hip/hip_bf16.h>
#include <stdint.h>

// Problem constants (B=4, T=2048, C=512, H=8, D=64)
constexpr int Bn = 4;
constexpr int Tn = 2048;
constexpr int Cn = 512;
constexpr int Hn = 8;
constexpr int Dn = 64;
constexpr int BT = Bn * Tn;          // 8192
constexpr int NQKV = 3 * Cn;         // 1536

typedef __attribute__((ext_vector_type(4))) float  f32x4;
typedef __attribute__((ext_vector_type(8))) short  s16x8;
typedef __attribute__((ext_vector_type(4))) short  s16x4;

__device__ __forceinline__ short f2bs(float f) {
    __hip_bfloat16 h = __float2bfloat16(f);
    return *reinterpret_cast<short*>(&h);
}
__device__ __forceinline__ float bs2f(short s) {
    uint32_t u = ((uint32_t)(uint16_t)s) << 16;
    return __builtin_bit_cast(float, u);
}

// ---------------- conversion / setup kernels ----------------

__global__ __launch_bounds__(256) void k_conv_x(const float* __restrict__ x,
                                                short* __restrict__ xb) {
    int i = blockIdx.x * 256 + threadIdx.x;          // one float4 per thread
    f32x4 v = reinterpret_cast<const f32x4*>(x)[i];
    s16x4 o;
    o[0] = f2bs(v[0]); o[1] = f2bs(v[1]); o[2] = f2bs(v[2]); o[3] = f2bs(v[3]);
    reinterpret_cast<s16x4*>(xb)[i] = o;
}

// w [512][N] fp32 -> wt [N][512] bf16
__global__ __launch_bounds__(256) void k_wT(const float* __restrict__ w,
                                            short* __restrict__ wt, int N) {
    int i = blockIdx.x * 256 + threadIdx.x;
    int k = i / N, n = i - k * N;
    wt[n * 512 + k] = f2bs(w[i]);
}

__global__ __launch_bounds__(256) void k_rope(float* __restrict__ cosT,
                                              float* __restrict__ sinT) {
    int i = blockIdx.x * 256 + threadIdx.x;          // < T*D
    int t = i >> 6, d = i & 63;
    // inv_freq = 10000^(-(d&31)/32) = exp2(-(d&31)*log2(10000)/32)
    float inv = exp2f(-(float)(d & 31) * 0.41524101186f);
    float fr = (float)t * inv;
    cosT[i] = cosf(fr);
    sinT[i] = sinf(fr);
}

// ---------------- GEMM (64x64 tile, 4 waves, 16x16x32 bf16 MFMA) ----------------
// A: [M][512] bf16 row-major.  Bt: [N][512] bf16 (pre-transposed weights).
// MODE 0: epilogue = RoPE + scatter Q/K to [B*H][T][D], V to transposed+permuted
//         Vt [B*H][D][Tperm] (fragment order for attn's PV B-operand).
// MODE 1: epilogue = plain fp32 store to out [M][512].

template <int MODE>
__global__ __launch_bounds__(256) void gemm_kernel(
    const short* __restrict__ A, const short* __restrict__ Bt,
    const float* __restrict__ cosT, const float* __restrict__ sinT,
    short* __restrict__ Qb, short* __restrict__ Kb, short* __restrict__ Vt,
    float* __restrict__ outF) {
    const int m0 = blockIdx.y * 64;
    const int n0 = blockIdx.x * 64;
    const int tid = threadIdx.x;
    const int w = tid >> 6, lane = tid & 63;
    const int qi = lane & 15, g = lane >> 4;

    // LDS layout: [colblk(4)][row(64)][8] — 16B per (colblk,row) chunk
    __shared__ short As[4 * 64 * 8];
    __shared__ short Bs[4 * 64 * 8];

    f32x4 acc[4];
#pragma unroll
    for (int nt = 0; nt < 4; ++nt) acc[nt] = (f32x4){0.f, 0.f, 0.f, 0.f};

    const int srow = tid >> 2, scb = tid & 3;

    for (int k0 = 0; k0 < 512; k0 += 32) {
        *(s16x8*)&As[(scb * 64 + srow) * 8] =
            *(const s16x8*)&A[(size_t)(m0 + srow) * 512 + k0 + scb * 8];
        *(s16x8*)&Bs[(scb * 64 + srow) * 8] =
            *(const s16x8*)&Bt[(size_t)(n0 + srow) * 512 + k0 + scb * 8];
        __syncthreads();
        s16x8 af = *(const s16x8*)&As[(g * 64 + 16 * w + qi) * 8];
#pragma unroll
        for (int nt = 0; nt < 4; ++nt) {
            s16x8 bf = *(const s16x8*)&Bs[(g * 64 + nt * 16 + qi) * 8];
            acc[nt] = __builtin_amdgcn_mfma_f32_16x16x32_bf16(af, bf, acc[nt], 0, 0, 0);
        }
        __syncthreads();
    }

    if (MODE == 1) {
#pragma unroll
        for (int nt = 0; nt < 4; ++nt)
#pragma unroll
            for (int r = 0; r < 4; ++r)
                outF[(size_t)(m0 + 16 * w + 4 * g + r) * 512 + n0 + nt * 16 + qi] =
                    acc[nt][r];
    } else {
        // n-tile (64 wide) lies entirely inside one {q,k,v} segment of one head
        const int h = n0 / 192;
        const int seg = (n0 >> 6) % 3;               // 0=q 1=k 2=v
        const int b = m0 >> 11;                      // m0 / 2048
        const int tb = (m0 & 2047) + 16 * w;
        if (seg == 2) {
            // V transposed + fragment-permuted: Vt[bh][d][ (t&~31) + g2*8 + sub2*4 + r2 ]
            const size_t vbase = (size_t)(b * Hn + h) * Dn;
#pragma unroll
            for (int nt = 0; nt < 4; ++nt)
#pragma unroll
                for (int r = 0; r < 4; ++r) {
                    int t = tb + 4 * g + r;
                    int d = nt * 16 + qi;
                    int o = t & 31;
                    int j = (t & ~31) + ((o >> 2) & 3) * 8 + (o >> 4) * 4 + (o & 3);
                    Vt[(vbase + d) * Tn + j] = f2bs(acc[nt][r]);
                }
        } else {
            short* dst = (seg == 0) ? Qb : Kb;
            const size_t headbase = (size_t)(b * Hn + h) * Tn;
#pragma unroll
            for (int nt = 0; nt < 4; ++nt)
#pragma unroll
                for (int r = 0; r < 4; ++r) {
                    int t = tb + 4 * g + r;
                    int d = nt * 16 + qi;
                    float val = acc[nt][r];
                    float pv = (nt < 2) ? -acc[nt + 2][r] : acc[nt - 2][r];
                    float cc = cosT[t * 64 + d], ss = sinT[t * 64 + d];
                    dst[(headbase + t) * Dn + d] = f2bs(val * cc + pv * ss);
                }
        }
    }
}

// ---------------- causal flash attention (split-K flash-decoding) ----------------
// Grid: 2048 blocks x 256 threads. Block = one (bh, 32-query tile); wave w = key
// split s. Each wave processes chunks [s*nch/4, (s+1)*nch/4) of the causal key
// range and emits UNNORMALIZED partials: O (bf16), (m,l) (fp32). No LDS, no
// barriers, no cross-wave traffic. Heaviest q-tiles dispatch first.
// Swapped QK^T: S^T = K·Q; softmax row = lane column qi, reduced across the 4
// lane-groups with shfl_xor. P stays lane-local for PV's A-operand; V is
// pre-transposed+permuted so PV's B-fragment is one 16B load.

__global__ __launch_bounds__(256) void attn_kernel(const short* __restrict__ Qb,
                                                   const short* __restrict__ Kb,
                                                   const short* __restrict__ Vt,
                                                   short* __restrict__ Opart,
                                                   float2* __restrict__ Ml) {
    const int gid = blockIdx.x;
    const int bh = gid & 31;
    const int qt = (Tn / 32 - 1) - (gid >> 5);
    const int tid = threadIdx.x;
    const int s = tid >> 6;                  // key-split id = wave id
    const int lane = tid & 63;
    const int qi = lane & 15, g = lane >> 4;
    const int qidx = (bh << 6) | qt;         // 0..2047

    const short* Qh = Qb + (size_t)bh * Tn * Dn;
    const short* Kh = Kb + (size_t)bh * Tn * Dn;
    const short* Vh = Vt + (size_t)bh * Dn * Tn;

    s16x8 qf[2][2];
#pragma unroll
    for (int qs = 0; qs < 2; ++qs)
#pragma unroll
        for (int dh = 0; dh < 2; ++dh)
            qf[qs][dh] = *(const s16x8*)&Qh[(size_t)(qt * 32 + qs * 16 + qi) * Dn +
                                            dh * 32 + g * 8];

    f32x4 O[2][4];
#pragma unroll
    for (int qs = 0; qs < 2; ++qs)
#pragma unroll
        for (int dt = 0; dt < 4; ++dt) O[qs][dt] = (f32x4){0.f, 0.f, 0.f, 0.f};
    float m[2] = {-1e30f, -1e30f};
    float l[2] = {0.f, 0.f};

    const float sc = 0.125f * 1.44269504f;   // 1/sqrt(D) * log2(e)
    const int nch = ((qt * 32 + 31) >> 6) + 1;
    const int lo = (s * nch) >> 2, hi = ((s + 1) * nch) >> 2;
    const f32x4 z4 = {0.f, 0.f, 0.f, 0.f};

    for (int ch = lo; ch < hi; ++ch) {
        const int kv0 = ch * 64;
        // ---- S^T = K·Q : 4 key-subtiles x 2 query-subtiles ----
        f32x4 sacc[2][4];
#pragma unroll
        for (int sub = 0; sub < 4; ++sub) {
            const size_t krow = (size_t)(kv0 + sub * 16 + qi) * Dn;
            s16x8 ka = *(const s16x8*)&Kh[krow + g * 8];
            s16x8 kc = *(const s16x8*)&Kh[krow + 32 + g * 8];
#pragma unroll
            for (int qs = 0; qs < 2; ++qs) {
                f32x4 t0 = __builtin_amdgcn_mfma_f32_16x16x32_bf16(ka, qf[qs][0], z4, 0, 0, 0);
                sacc[qs][sub] = __builtin_amdgcn_mfma_f32_16x16x32_bf16(kc, qf[qs][1], t0, 0, 0, 0);
            }
        }

        s16x8 pf[2][2];
#pragma unroll
        for (int qs = 0; qs < 2; ++qs) {
            const int qsbase = qt * 32 + qs * 16;
            const int qrow = qsbase + qi;
            float sv[16];
            if (kv0 + 63 <= qsbase) {           // interior chunk: no masking needed
#pragma unroll
                for (int e = 0; e < 16; ++e) sv[e] = sacc[qs][e >> 2][e & 3] * sc;
            } else {
#pragma unroll
                for (int sub = 0; sub < 4; ++sub)
#pragma unroll
                    for (int r = 0; r < 4; ++r) {
                        int key = kv0 + sub * 16 + 4 * g + r;
                        sv[sub * 4 + r] = (key <= qrow) ? sacc[qs][sub][r] * sc : -1e30f;
                    }
            }
            // row max (row = query qi; reduce in-lane then across 4 g-groups)
            float pm = sv[0];
#pragma unroll
            for (int e = 1; e < 16; ++e) pm = fmaxf(pm, sv[e]);
            pm = fmaxf(pm, __shfl_xor(pm, 16));
            pm = fmaxf(pm, __shfl_xor(pm, 32));
            float mn = m[qs];
            if (!__all(pm <= mn + 8.0f)) {      // defer-max (log2 domain, THR=8)
                mn = fmaxf(mn, pm);
                float f = exp2f(m[qs] - mn);
                m[qs] = mn;
                l[qs] *= f;
#pragma unroll
                for (int r = 0; r < 4; ++r) {
                    float fr = __shfl(f, 4 * g + r);
#pragma unroll
                    for (int dt = 0; dt < 4; ++dt) O[qs][dt][r] *= fr;
                }
            }
            float ps = 0.f;
#pragma unroll
            for (int e = 0; e < 16; ++e) { sv[e] = exp2f(sv[e] - mn); ps += sv[e]; }
            ps += __shfl_xor(ps, 16);
            ps += __shfl_xor(ps, 32);
            l[qs] += ps;
#pragma unroll
            for (int c = 0; c < 2; ++c)
#pragma unroll
                for (int e = 0; e < 8; ++e) pf[qs][c][e] = f2bs(sv[c * 8 + e]);
        }

        // ---- O += P·V (V fragment = one 16B load from permuted Vt) ----
#pragma unroll
        for (int c = 0; c < 2; ++c)
#pragma unroll
            for (int dt = 0; dt < 4; ++dt) {
                s16x8 vf = *(const s16x8*)&Vh[(size_t)(dt * 16 + qi) * Tn +
                                              kv0 + c * 32 + g * 8];
#pragma unroll
                for (int qs = 0; qs < 2; ++qs)
                    O[qs][dt] = __builtin_amdgcn_mfma_f32_16x16x32_bf16(
                        pf[qs][c], vf, O[qs][dt], 0, 0, 0);
            }
    }

    // ---- store UNNORMALIZED partials (every wave, even empty splits) ----
    const size_t pbase = ((size_t)qidx * 4 + s) * 32;
    if (g == 0) {
        Ml[pbase + qi]      = make_float2(m[0], l[0]);
        Ml[pbase + 16 + qi] = make_float2(m[1], l[1]);
    }
#pragma unroll
    for (int qs = 0; qs < 2; ++qs)
#pragma unroll
        for (int r = 0; r < 4; ++r) {
            int rl = qs * 16 + 4 * g + r;
#pragma unroll
            for (int dt = 0; dt < 4; ++dt)
                Opart[(pbase + rl) * 64 + dt * 16 + qi] = f2bs(O[qs][dt][r]);
        }
}

// ---------------- split-K combine ----------------
// Block per (bh, qtile); thread (q = tid/8, d-octet = tid%8). Merges 4 partials:
// M = max m_s;  L = sum l_s*2^(m_s-M);  O = sum O_s*2^(m_s-M) / L.

__global__ __launch_bounds__(256) void combine_kernel(const short* __restrict__ Opart,
                                                      const float2* __restrict__ Ml,
                                                      short* __restrict__ AO) {
    const int qidx = blockIdx.x;
    const int tid = threadIdx.x;
    const int q = tid >> 3;
    const int d0 = (tid & 7) * 8;

    float ms[4], ls[4];
#pragma unroll
    for (int s = 0; s < 4; ++s) {
        float2 ml = Ml[((size_t)qidx * 4 + s) * 32 + q];
        ms[s] = ml.x; ls[s] = ml.y;
    }
    float M = fmaxf(fmaxf(ms[0], ms[1]), fmaxf(ms[2], ms[3]));
    float wsc[4]; float L = 0.f;
#pragma unroll
    for (int s = 0; s < 4; ++s) { wsc[s] = exp2f(ms[s] - M); L += ls[s] * wsc[s]; }
    float invL = 1.f / L;

    float acc[8] = {0, 0, 0, 0, 0, 0, 0, 0};
#pragma unroll
    for (int s = 0; s < 4; ++s) {
        s16x8 o = *(const s16x8*)&Opart[(((size_t)qidx * 4 + s) * 32 + q) * 64 + d0];
#pragma unroll
        for (int j = 0; j < 8; ++j) acc[j] += bs2f(o[j]) * wsc[s];
    }

    const int qt = qidx & 63, bh = qidx >> 6;
    const int b = bh >> 3, h = bh & 7;
    const int t = qt * 32 + q;
    s16x8 outv;
#pragma unroll
    for (int j = 0; j < 8; ++j) outv[j] = f2bs(acc[j] * invL);
    *(s16x8*)&AO[((size_t)(b * Tn + t)) * Cn + h * 64 + d0] = outv;
}

// ---------------- launcher ----------------

extern "C" void kernel_launch(void* const* d_in, const int* in_sizes, int n_in,
                              void* d_out, int out_size, void* d_ws, size_t ws_size,
                              hipStream_t stream) {
    const float* x = (const float*)d_in[0];
    const float* Wqkv = (const float*)d_in[1];
    const float* Wproj = (const float*)d_in[2];
    float* out = (float*)d_out;

    char* ws = (char*)d_ws;
    size_t o = 0;
    short* xb = (short*)(ws + o);      o += (size_t)BT * Cn * 2;      // 8MB (aliased as AO later)
    short* wqkvT = (short*)(ws + o);   o += (size_t)NQKV * Cn * 2;    // 1.5MB
    short* wprojT = (short*)(ws + o);  o += (size_t)Cn * Cn * 2;      // 0.5MB
    short* Qb = (short*)(ws + o);      o += (size_t)Bn * Hn * Tn * Dn * 2;  // 8MB
    short* Kb = (short*)(ws + o);      o += (size_t)Bn * Hn * Tn * Dn * 2;  // 8MB
    short* Vt = (short*)(ws + o);      o += (size_t)Bn * Hn * Tn * Dn * 2;  // 8MB
    float* cosT = (float*)(ws + o);    o += (size_t)Tn * Dn * 4;      // 0.5MB
    float* sinT = (float*)(ws + o);    o += (size_t)Tn * Dn * 4;      // 0.5MB
    short* Opart = (short*)(ws + o);   o += (size_t)2048 * 4 * 32 * 64 * 2;  // 32MB
    float2* Ml = (float2*)(ws + o);    o += (size_t)2048 * 4 * 32 * 8;       // 2MB

    k_conv_x<<<BT * Cn / 4 / 256, 256, 0, stream>>>(x, xb);
    k_wT<<<512 * NQKV / 256, 256, 0, stream>>>(Wqkv, wqkvT, NQKV);
    k_wT<<<512 * Cn / 256, 256, 0, stream>>>(Wproj, wprojT, Cn);
    k_rope<<<Tn * Dn / 256, 256, 0, stream>>>(cosT, sinT);

    gemm_kernel<0><<<dim3(NQKV / 64, BT / 64), 256, 0, stream>>>(
        xb, wqkvT, cosT, sinT, Qb, Kb, Vt, nullptr);

    attn_kernel<<<dim3(Tn / 32 * 32), 256, 0, stream>>>(Qb, Kb, Vt, Opart, Ml);

    combine_kernel<<<dim3(2048), 256, 0, stream>>>(Opart, Ml, xb /*AO alias*/);

    gemm_kernel<1><<<dim3(Cn / 64, BT / 64), 256, 0, stream>>>(
        xb /*AO*/, wprojT, nullptr, nullptr, nullptr, nullptr, nullptr, out);
}